// Round 22
// baseline (2346.542 us; speedup 1.0000x reference)
//
#include <hip/hip_runtime.h>
#include <hip/hip_bf16.h>
#include <math.h>

typedef __attribute__((ext_vector_type(8))) short bf16x8;
typedef __attribute__((ext_vector_type(4))) float f32x4;
typedef __attribute__((ext_vector_type(4))) unsigned short u16x4;

#define B_   16
#define C_   128
#define CHW_ 131072   // 128*32*32
#define STR_ 138      // LDS pixel stride in shorts (69 dwords, odd -> bank spread)

__device__ __forceinline__ unsigned short f2bf(float f) {
  union { float f; unsigned int i; } v; v.f = f;
  unsigned int lsb = (v.i >> 16) & 1u;
  v.i += 0x7fffu + lsb;
  return (unsigned short)(v.i >> 16);
}

// fast tanh: 1 - 2/(e^{2x}+1). Saturates correctly at +/-inf.
__device__ __forceinline__ float fast_tanh(float x) {
  float e = __expf(2.f * x);
  return 1.f - 2.f * __builtin_amdgcn_rcpf(e + 1.f);
}

// ---- weight prep: W[O][I][3][3] f32 -> wpk[ks][co][ci&31] bf16, ks = off*4 + (ci>>5)
__global__ void prep_weights(const float* __restrict__ W1, const float* __restrict__ W2,
                             unsigned short* __restrict__ w1bf, unsigned short* __restrict__ w2bf) {
  int j = blockIdx.x * 256 + threadIdx.x;
  if (j >= 2 * 147456) return;
  int which = j / 147456;
  int r = j - which * 147456;
  int ks = r >> 12;
  int co = (r >> 5) & 127;
  int c5 = r & 31;
  int off = ks >> 2;
  int ci  = (ks & 3) * 32 + c5;
  const float* src = which ? W2 : W1;
  unsigned short* dst = which ? w2bf : w1bf;
  dst[r] = f2bf(src[(co * 128 + ci) * 9 + off]);
}

// ---- init: dout[:,t=0,...] = y0 (NCHW pass-through)
__global__ void init_copy(const float* __restrict__ y0, float* __restrict__ dout) {
  int i = blockIdx.x * 256 + threadIdx.x;
  if (i >= B_ * CHW_) return;
  int b = i >> 17, chw = i & (CHW_ - 1);
  dout[b * 25 * CHW_ + chw] = y0[i];
}

// ---- init: tmp_bf (NHWC bf16) and y32f (NHWC f32) = transpose(y0)
__global__ void init_transpose(const float* __restrict__ y0, unsigned short* __restrict__ tmp_bf,
                               float* __restrict__ y32f) {
  __shared__ float t[32][33];
  int blk = blockIdx.x;          // 16 b * 4 co-tiles * 32 pix-tiles = 2048
  int b = blk >> 7;
  int rem = blk & 127;
  int co0 = (rem >> 5) * 32;
  int p0  = (rem & 31) * 32;
  int tx = threadIdx.x & 31, ty = threadIdx.x >> 5;
  #pragma unroll
  for (int k = 0; k < 4; k++) {
    int cl = ty + k * 8;
    t[cl][tx] = y0[b * CHW_ + (co0 + cl) * 1024 + p0 + tx];
  }
  __syncthreads();
  #pragma unroll
  for (int k = 0; k < 4; k++) {
    int pl = ty + k * 8;
    float v = t[tx][pl];
    int idx = (b * 1024 + p0 + pl) * 128 + co0 + tx;
    tmp_bf[idx] = f2bf(v);
    y32f[idx] = v;
  }
}

// ---- fused RK4 stage kernel (multi-launch, plain cached loads). r15 structure
// (A-minimal wave partition: each wave owns ONE 16-co fragment + whole spatial
// tile -> block A traffic = |W1|+|W2| = 576 KB, the proven minimum), with
// y32/acc32 in NHWC f32 so the epilogue is coalesced f32x4 (isolated change).
// conv1 wave: 16co x 4 zrows x 32 cols, acc[4][2]; per (dw,kk): 3A + 12B -> 24 MFMA.
// conv2 wave: 16co x 2 rows  x 32 cols, acc[2][2]; per (dw,kk): 3A +  8B -> 12 MFMA.
// Grid: 16 images x 16 rowpairs = 256 blocks (1/CU), 512 thr (8 waves).
template<int ST>
__global__ __launch_bounds__(512, 1)
void fused_stage(const unsigned short* __restrict__ w1bf,
                 const unsigned short* __restrict__ w2bf,
                 const float* __restrict__ b1v, const float* __restrict__ b2v,
                 unsigned short* __restrict__ tmp_bf,
                 float* __restrict__ y32f, float* __restrict__ acc32f,
                 float* __restrict__ dout, const float* __restrict__ tarr, int step)
{
  // IT: tmp tile, 6 rows (r0-2..r0+3) x 34 cols x 128 ci, pixel stride 138
  // ZT: z tile,   4 rows (r0-1..r0+2) x 34 cols x 128 co (LDS-only)
  __shared__ unsigned short IT[204 * STR_];
  __shared__ unsigned short ZT[136 * STR_];
  const int tid  = threadIdx.x;
  const int img  = blockIdx.x >> 4;
  const int r0   = (blockIdx.x & 15) * 2;
  const int lane = tid & 63;
  const int wave = tid >> 6;          // = co-fragment index (0..7)
  const int lhi  = lane >> 4;         // 0..3 (K octet / D row group)
  const int llo  = lane & 15;         // A: co row, B: sp col, D: col

  const unsigned short* a1base = w1bf + (wave * 16 + llo) * 32 + lhi * 8;
  const unsigned short* a2base = w2bf + (wave * 16 + llo) * 32 + lhi * 8;

  float t0 = tarr[step];
  float t1 = tarr[step + 1];
  // keep one operand in a VGPR: avoids V_ADD_F32 with two SGPR sources
  // (constant-bus violation -> backend compile error on gfx950)
  asm volatile("" : "+v"(t1));
  const float dt = t1 - t0;
  const float dt6 = dt * (1.f / 6.f), dt3 = dt * (1.f / 3.f), dth = dt * 0.5f;

  // ---- stage tmp tile (6 rows, zero-padded halo) + zero ZT col pads
  for (int chunk = tid; chunk < 204 * 16 + 128; chunk += 512) {
    if (chunk < 204 * 16) {
      int pix = chunk >> 4;
      int oct = chunk & 15;
      int ir = pix / 34, ic = pix - ir * 34;
      int gr = r0 - 2 + ir, gc = ic - 1;
      bf16x8 v = {0, 0, 0, 0, 0, 0, 0, 0};
      if ((unsigned)gr < 32u && (unsigned)gc < 32u)
        v = *(const bf16x8*)(tmp_bf + ((img * 32 + gr) * 32 + gc) * 128 + oct * 8);
      *(bf16x8*)(IT + pix * STR_ + oct * 8) = v;
    } else {
      int padidx = chunk - 204 * 16;      // 0..127 : 4 zrows x 2 sides x 16 oct
      int zp  = padidx >> 4;
      int oct = padidx & 15;
      int zpix = (zp >> 1) * 34 + ((zp & 1) ? 33 : 0);
      bf16x8 z = {0, 0, 0, 0, 0, 0, 0, 0};
      *(bf16x8*)(ZT + zpix * STR_ + oct * 8) = z;
    }
  }
  __syncthreads();

  // ---- conv1: z = tanh(conv(tmp,W1)+b1), wave computes 16co x 4 zrows x 32 cols
  {
    const int co = wave * 16 + lhi * 4;
    f32x4 bia = *(const f32x4*)(b1v + co);   // hoisted bias load
    f32x4 a1[4][2];   // [zr][spt]
    #pragma unroll
    for (int i = 0; i < 4; i++) { a1[i][0] = (f32x4){0,0,0,0}; a1[i][1] = (f32x4){0,0,0,0}; }
    #pragma unroll
    for (int dw = 0; dw < 3; ++dw) {
      #pragma unroll
      for (int kk = 0; kk < 4; ++kk) {
        // 6 distinct input rows x 2 col-halves, shared across dh and zr
        bf16x8 bfr[6][2];
        #pragma unroll
        for (int rr = 0; rr < 6; ++rr) {
          const int prow = rr * 34 + llo + dw;
          bfr[rr][0] = *(const bf16x8*)(IT + prow * STR_ + kk * 32 + lhi * 8);
          bfr[rr][1] = *(const bf16x8*)(IT + (prow + 16) * STR_ + kk * 32 + lhi * 8);
        }
        bf16x8 afr[3];
        #pragma unroll
        for (int dh = 0; dh < 3; ++dh)
          afr[dh] = *(const bf16x8*)(a1base + ((dh * 3 + dw) * 4 + kk) * 4096);
        #pragma unroll
        for (int dh = 0; dh < 3; ++dh)
          #pragma unroll
          for (int zr = 0; zr < 4; ++zr)
            #pragma unroll
            for (int spt = 0; spt < 2; ++spt)
              a1[zr][spt] = __builtin_amdgcn_mfma_f32_16x16x32_bf16(afr[dh], bfr[zr + dh][spt], a1[zr][spt], 0, 0, 0);
      }
    }
    #pragma unroll
    for (int zr = 0; zr < 4; ++zr) {
      const bool live = (unsigned)(r0 - 1 + zr) < 32u;
      #pragma unroll
      for (int spt = 0; spt < 2; ++spt) {
        const int c = spt * 16 + llo;
        u16x4 pk;
        #pragma unroll
        for (int reg = 0; reg < 4; ++reg)
          pk[reg] = live ? f2bf(fast_tanh(a1[zr][spt][reg] + bia[reg])) : (unsigned short)0;
        *(u16x4*)(ZT + (zr * 34 + c + 1) * STR_ + co) = pk;
      }
    }
  }
  __syncthreads();

  // ---- conv2: k = conv(z,W2)+b2, wave computes 16co x 2 rows x 32 cols + RK4
  {
    const int co0 = wave * 16 + lhi * 4;
    f32x4 bia = *(const f32x4*)(b2v + co0);
    // prefetch epilogue state BEFORE the K-loop (NHWC f32x4, coalesced):
    // latency hides under 144 MFMAs
    f32x4 ypre[2][2], apre[2][2];
    #pragma unroll
    for (int q = 0; q < 2; ++q)
      #pragma unroll
      for (int spt = 0; spt < 2; ++spt) {
        const int pnhwc = (img * 1024 + (r0 + q) * 32 + spt * 16 + llo) * 128 + co0;
        if constexpr (ST <= 3) ypre[q][spt] = *(const f32x4*)(y32f + pnhwc);
        if constexpr (ST >= 2) apre[q][spt] = *(const f32x4*)(acc32f + pnhwc);
      }

    f32x4 a2[2][2];   // [q(row)][spt]
    #pragma unroll
    for (int i = 0; i < 2; i++) { a2[i][0] = (f32x4){0,0,0,0}; a2[i][1] = (f32x4){0,0,0,0}; }
    #pragma unroll
    for (int dw = 0; dw < 3; ++dw) {
      #pragma unroll
      for (int kk = 0; kk < 4; ++kk) {
        bf16x8 bfr[4][2];
        #pragma unroll
        for (int rr = 0; rr < 4; ++rr) {
          const int zpix = rr * 34 + llo + dw;
          bfr[rr][0] = *(const bf16x8*)(ZT + zpix * STR_ + kk * 32 + lhi * 8);
          bfr[rr][1] = *(const bf16x8*)(ZT + (zpix + 16) * STR_ + kk * 32 + lhi * 8);
        }
        bf16x8 afr[3];
        #pragma unroll
        for (int dh = 0; dh < 3; ++dh)
          afr[dh] = *(const bf16x8*)(a2base + ((dh * 3 + dw) * 4 + kk) * 4096);
        #pragma unroll
        for (int dh = 0; dh < 3; ++dh)
          #pragma unroll
          for (int q = 0; q < 2; ++q)
            #pragma unroll
            for (int spt = 0; spt < 2; ++spt)
              a2[q][spt] = __builtin_amdgcn_mfma_f32_16x16x32_bf16(afr[dh], bfr[q + dh][spt], a2[q][spt], 0, 0, 0);
      }
    }

    #pragma unroll
    for (int q = 0; q < 2; ++q) {
      const int row = r0 + q;
      #pragma unroll
      for (int spt = 0; spt < 2; ++spt) {
        const int col = spt * 16 + llo;
        const int pnhwc = (img * 1024 + row * 32 + col) * 128 + co0;
        f32x4 kv, tv;
        #pragma unroll
        for (int reg = 0; reg < 4; ++reg) kv[reg] = a2[q][spt][reg] + bia[reg];
        if constexpr (ST == 1) {
          f32x4 yv = ypre[q][spt], av;
          #pragma unroll
          for (int reg = 0; reg < 4; ++reg) { av[reg] = yv[reg] + dt6 * kv[reg]; tv[reg] = yv[reg] + dth * kv[reg]; }
          *(f32x4*)(acc32f + pnhwc) = av;
        } else if constexpr (ST == 2) {
          f32x4 yv = ypre[q][spt], av = apre[q][spt];
          #pragma unroll
          for (int reg = 0; reg < 4; ++reg) { av[reg] += dt3 * kv[reg]; tv[reg] = yv[reg] + dth * kv[reg]; }
          *(f32x4*)(acc32f + pnhwc) = av;
        } else if constexpr (ST == 3) {
          f32x4 yv = ypre[q][spt], av = apre[q][spt];
          #pragma unroll
          for (int reg = 0; reg < 4; ++reg) { av[reg] += dt3 * kv[reg]; tv[reg] = yv[reg] + dt * kv[reg]; }
          *(f32x4*)(acc32f + pnhwc) = av;
        } else {
          f32x4 av = apre[q][spt];
          #pragma unroll
          for (int reg = 0; reg < 4; ++reg) tv[reg] = av[reg] + dt6 * kv[reg];
          *(f32x4*)(y32f + pnhwc) = tv;
          const long dbase = (long)(img * 25 + step + 1) * CHW_ + co0 * 1024 + row * 32 + col;
          #pragma unroll
          for (int reg = 0; reg < 4; ++reg) dout[dbase + reg * 1024] = tv[reg];
        }
        u16x4 pk;
        #pragma unroll
        for (int reg = 0; reg < 4; ++reg) pk[reg] = f2bf(tv[reg]);
        *(u16x4*)(tmp_bf + pnhwc) = pk;
      }
    }
  }
}

extern "C" void kernel_launch(void* const* d_in, const int* in_sizes, int n_in,
                              void* d_out, int out_size, void* d_ws, size_t ws_size,
                              hipStream_t stream) {
  const float* y0   = (const float*)d_in[0];
  const float* tarr = (const float*)d_in[1];
  const float* W1   = (const float*)d_in[2];
  const float* b1   = (const float*)d_in[3];
  const float* W2   = (const float*)d_in[4];
  const float* b2   = (const float*)d_in[5];
  float* dout = (float*)d_out;

  char* ws = (char*)d_ws;
  float* y32f            = (float*)(ws);                          // 8 MB (NHWC)
  float* acc32f          = (float*)(ws + (8u << 20));             // 8 MB (NHWC)
  unsigned short* tmp_bf = (unsigned short*)(ws + (16u << 20));   // 4 MB (NHWC)
  unsigned short* w1bf   = (unsigned short*)(ws + (20u << 20));   // 288 KB
  unsigned short* w2bf   = (unsigned short*)(ws + (20u << 20) + 294912);

  prep_weights<<<(2 * 147456 + 255) / 256, 256, 0, stream>>>(W1, W2, w1bf, w2bf);
  init_copy<<<(B_ * CHW_ + 255) / 256, 256, 0, stream>>>(y0, dout);
  init_transpose<<<2048, 256, 0, stream>>>(y0, tmp_bf, y32f);

  for (int step = 0; step < 24; ++step) {
    fused_stage<1><<<256, 512, 0, stream>>>(w1bf, w2bf, b1, b2, tmp_bf, y32f, acc32f, dout, tarr, step);
    fused_stage<2><<<256, 512, 0, stream>>>(w1bf, w2bf, b1, b2, tmp_bf, y32f, acc32f, dout, tarr, step);
    fused_stage<3><<<256, 512, 0, stream>>>(w1bf, w2bf, b1, b2, tmp_bf, y32f, acc32f, dout, tarr, step);
    fused_stage<4><<<256, 512, 0, stream>>>(w1bf, w2bf, b1, b2, tmp_bf, y32f, acc32f, dout, tarr, step);
  }
}

// Round 23
// 2241.438 us; speedup vs baseline: 1.0469x; 1.0469x over previous
//
#include <hip/hip_runtime.h>
#include <hip/hip_bf16.h>
#include <math.h>

typedef __attribute__((ext_vector_type(8))) short bf16x8;
typedef __attribute__((ext_vector_type(4))) float f32x4;
typedef __attribute__((ext_vector_type(4))) unsigned short u16x4;

#define B_   16
#define C_   128
#define CHW_ 131072   // 128*32*32
#define STR_ 138      // LDS pixel stride in shorts (69 dwords, gcd(69,32)=1 -> conflict-free spread)

__device__ __forceinline__ unsigned short f2bf(float f) {
  union { float f; unsigned int i; } v; v.f = f;
  unsigned int lsb = (v.i >> 16) & 1u;
  v.i += 0x7fffu + lsb;
  return (unsigned short)(v.i >> 16);
}

// fast tanh: 1 - 2/(e^{2x}+1). __expf -> v_exp; rcp ~1e-6 rel err (bf16-irrelevant).
// Saturates correctly: x>>0 -> e=inf -> rcp=0 -> 1; x<<0 -> e=0 -> -1.
__device__ __forceinline__ float fast_tanh(float x) {
  float e = __expf(2.f * x);
  return 1.f - 2.f * __builtin_amdgcn_rcpf(e + 1.f);
}

// ---- weight prep: W[O][I][3][3] f32 -> wpk[ks][co][ci&31] bf16, ks = off*4 + (ci>>5)
__global__ void prep_weights(const float* __restrict__ W1, const float* __restrict__ W2,
                             unsigned short* __restrict__ w1bf, unsigned short* __restrict__ w2bf) {
  int j = blockIdx.x * 256 + threadIdx.x;
  if (j >= 2 * 147456) return;
  int which = j / 147456;
  int r = j - which * 147456;
  int ks = r >> 12;
  int co = (r >> 5) & 127;
  int c5 = r & 31;
  int off = ks >> 2;
  int ci  = (ks & 3) * 32 + c5;
  const float* src = which ? W2 : W1;
  unsigned short* dst = which ? w2bf : w1bf;
  dst[r] = f2bf(src[(co * 128 + ci) * 9 + off]);
}

// ---- init: y32 = y0 (NCHW f32); dout[:,t=0,...] = y0
__global__ void init_copy(const float* __restrict__ y0, float* __restrict__ y32,
                          float* __restrict__ dout) {
  int i = blockIdx.x * 256 + threadIdx.x;
  if (i >= B_ * CHW_) return;
  float v = y0[i];
  y32[i] = v;
  int b = i >> 17, chw = i & (CHW_ - 1);
  dout[b * 25 * CHW_ + chw] = v;
}

// ---- init: tmp_bf (NHWC bf16) = transpose(y0)
__global__ void init_transpose(const float* __restrict__ y0, unsigned short* __restrict__ tmp_bf) {
  __shared__ float t[32][33];
  int blk = blockIdx.x;          // 16 b * 4 co-tiles * 32 pix-tiles = 2048
  int b = blk >> 7;
  int rem = blk & 127;
  int co0 = (rem >> 5) * 32;
  int p0  = (rem & 31) * 32;
  int tx = threadIdx.x & 31, ty = threadIdx.x >> 5;
  #pragma unroll
  for (int k = 0; k < 4; k++) {
    int cl = ty + k * 8;
    t[cl][tx] = y0[b * CHW_ + (co0 + cl) * 1024 + p0 + tx];
  }
  __syncthreads();
  #pragma unroll
  for (int k = 0; k < 4; k++) {
    int pl = ty + k * 8;
    tmp_bf[(b * 1024 + p0 + pl) * 128 + co0 + tx] = f2bf(t[tx][pl]);
  }
}

// ---- fused RK4 stage kernel (multi-launch, plain cached loads). FINAL (r15):
// weight-traffic-minimal wave partition (each wave owns ONE 16-co fragment and
// the whole spatial tile; block A traffic = |W1|+|W2| = 576 KB, minimal) +
// epilogue prefetch under conv2, fast tanh, stride-138 LDS.
// Grid: 16 images x 16 rowpairs = 256 blocks (1/CU), 512 thr (8 waves).
// conv1 wave: 16co x 4 zrows x 32 cols, acc[4][2]; per (dw,kk): 3A + 12B -> 24 MFMA.
// conv2 wave: 16co x 2 rows  x 32 cols, acc[2][2]; per (dw,kk): 3A +  8B -> 12 MFMA.
template<int ST>
__global__ __launch_bounds__(512, 1)
void fused_stage(const unsigned short* __restrict__ w1bf,
                 const unsigned short* __restrict__ w2bf,
                 const float* __restrict__ b1v, const float* __restrict__ b2v,
                 unsigned short* __restrict__ tmp_bf,
                 float* __restrict__ y32, float* __restrict__ acc32,
                 float* __restrict__ dout, const float* __restrict__ tarr, int step)
{
  // IT: tmp tile, 6 rows (r0-2..r0+3) x 34 cols x 128 ci, pixel stride 138
  // ZT: z tile,   4 rows (r0-1..r0+2) x 34 cols x 128 co (LDS-only)
  __shared__ unsigned short IT[204 * STR_];
  __shared__ unsigned short ZT[136 * STR_];
  const int tid  = threadIdx.x;
  const int img  = blockIdx.x >> 4;
  const int r0   = (blockIdx.x & 15) * 2;
  const int lane = tid & 63;
  const int wave = tid >> 6;          // = co-fragment index (0..7)
  const int lhi  = lane >> 4;         // 0..3 (K octet / D row group)
  const int llo  = lane & 15;         // A: co row, B: sp col, D: col

  const unsigned short* a1base = w1bf + (wave * 16 + llo) * 32 + lhi * 8;
  const unsigned short* a2base = w2bf + (wave * 16 + llo) * 32 + lhi * 8;

  float t0 = tarr[step];
  float t1 = tarr[step + 1];
  // keep one operand in a VGPR: avoids V_ADD_F32 with two SGPR sources
  // (constant-bus violation -> backend compile error on gfx950)
  asm volatile("" : "+v"(t1));
  const float dt = t1 - t0;
  const float dt6 = dt * (1.f / 6.f), dt3 = dt * (1.f / 3.f), dth = dt * 0.5f;

  // ---- stage tmp tile (6 rows, zero-padded halo) + zero ZT col pads
  for (int chunk = tid; chunk < 204 * 16 + 128; chunk += 512) {
    if (chunk < 204 * 16) {
      int pix = chunk >> 4;
      int oct = chunk & 15;
      int ir = pix / 34, ic = pix - ir * 34;
      int gr = r0 - 2 + ir, gc = ic - 1;
      bf16x8 v = {0, 0, 0, 0, 0, 0, 0, 0};
      if ((unsigned)gr < 32u && (unsigned)gc < 32u)
        v = *(const bf16x8*)(tmp_bf + ((img * 32 + gr) * 32 + gc) * 128 + oct * 8);
      *(bf16x8*)(IT + pix * STR_ + oct * 8) = v;
    } else {
      int padidx = chunk - 204 * 16;      // 0..127 : 4 zrows x 2 sides x 16 oct
      int zp  = padidx >> 4;
      int oct = padidx & 15;
      int zpix = (zp >> 1) * 34 + ((zp & 1) ? 33 : 0);
      bf16x8 z = {0, 0, 0, 0, 0, 0, 0, 0};
      *(bf16x8*)(ZT + zpix * STR_ + oct * 8) = z;
    }
  }
  __syncthreads();

  // ---- conv1: z = tanh(conv(tmp,W1)+b1), wave computes 16co x 4 zrows x 32 cols
  {
    const int co = wave * 16 + lhi * 4;
    f32x4 bia = *(const f32x4*)(b1v + co);   // hoisted bias load
    f32x4 a1[4][2];   // [zr][spt]
    #pragma unroll
    for (int i = 0; i < 4; i++) { a1[i][0] = (f32x4){0,0,0,0}; a1[i][1] = (f32x4){0,0,0,0}; }
    #pragma unroll
    for (int dw = 0; dw < 3; ++dw) {
      #pragma unroll
      for (int kk = 0; kk < 4; ++kk) {
        // 6 distinct input rows x 2 col-halves, shared across dh and zr
        bf16x8 bfr[6][2];
        #pragma unroll
        for (int rr = 0; rr < 6; ++rr) {
          const int prow = rr * 34 + llo + dw;
          bfr[rr][0] = *(const bf16x8*)(IT + prow * STR_ + kk * 32 + lhi * 8);
          bfr[rr][1] = *(const bf16x8*)(IT + (prow + 16) * STR_ + kk * 32 + lhi * 8);
        }
        bf16x8 afr[3];
        #pragma unroll
        for (int dh = 0; dh < 3; ++dh)
          afr[dh] = *(const bf16x8*)(a1base + ((dh * 3 + dw) * 4 + kk) * 4096);
        #pragma unroll
        for (int dh = 0; dh < 3; ++dh)
          #pragma unroll
          for (int zr = 0; zr < 4; ++zr)
            #pragma unroll
            for (int spt = 0; spt < 2; ++spt)
              a1[zr][spt] = __builtin_amdgcn_mfma_f32_16x16x32_bf16(afr[dh], bfr[zr + dh][spt], a1[zr][spt], 0, 0, 0);
      }
    }
    #pragma unroll
    for (int zr = 0; zr < 4; ++zr) {
      const bool live = (unsigned)(r0 - 1 + zr) < 32u;
      #pragma unroll
      for (int spt = 0; spt < 2; ++spt) {
        const int c = spt * 16 + llo;
        u16x4 pk;
        #pragma unroll
        for (int reg = 0; reg < 4; ++reg)
          pk[reg] = live ? f2bf(fast_tanh(a1[zr][spt][reg] + bia[reg])) : (unsigned short)0;
        *(u16x4*)(ZT + (zr * 34 + c + 1) * STR_ + co) = pk;
      }
    }
  }
  __syncthreads();

  // ---- conv2: k = conv(z,W2)+b2, wave computes 16co x 2 rows x 32 cols + RK4
  {
    const int co0 = wave * 16 + lhi * 4;
    f32x4 bia = *(const f32x4*)(b2v + co0);
    // prefetch epilogue state BEFORE the K-loop: latency hides under 144 MFMAs
    float ypre[2][2][4], apre[2][2][4];
    #pragma unroll
    for (int q = 0; q < 2; ++q)
      #pragma unroll
      for (int spt = 0; spt < 2; ++spt) {
        const int idx0 = img * CHW_ + co0 * 1024 + (r0 + q) * 32 + spt * 16 + llo;
        #pragma unroll
        for (int reg = 0; reg < 4; ++reg) {
          if constexpr (ST <= 3) ypre[q][spt][reg] = y32[idx0 + reg * 1024];
          if constexpr (ST >= 2) apre[q][spt][reg] = acc32[idx0 + reg * 1024];
        }
      }

    f32x4 a2[2][2];   // [q(row)][spt]
    #pragma unroll
    for (int i = 0; i < 2; i++) { a2[i][0] = (f32x4){0,0,0,0}; a2[i][1] = (f32x4){0,0,0,0}; }
    #pragma unroll
    for (int dw = 0; dw < 3; ++dw) {
      #pragma unroll
      for (int kk = 0; kk < 4; ++kk) {
        bf16x8 bfr[4][2];
        #pragma unroll
        for (int rr = 0; rr < 4; ++rr) {
          const int zpix = rr * 34 + llo + dw;
          bfr[rr][0] = *(const bf16x8*)(ZT + zpix * STR_ + kk * 32 + lhi * 8);
          bfr[rr][1] = *(const bf16x8*)(ZT + (zpix + 16) * STR_ + kk * 32 + lhi * 8);
        }
        bf16x8 afr[3];
        #pragma unroll
        for (int dh = 0; dh < 3; ++dh)
          afr[dh] = *(const bf16x8*)(a2base + ((dh * 3 + dw) * 4 + kk) * 4096);
        #pragma unroll
        for (int dh = 0; dh < 3; ++dh)
          #pragma unroll
          for (int q = 0; q < 2; ++q)
            #pragma unroll
            for (int spt = 0; spt < 2; ++spt)
              a2[q][spt] = __builtin_amdgcn_mfma_f32_16x16x32_bf16(afr[dh], bfr[q + dh][spt], a2[q][spt], 0, 0, 0);
      }
    }

    #pragma unroll
    for (int q = 0; q < 2; ++q) {
      const int row = r0 + q;
      #pragma unroll
      for (int spt = 0; spt < 2; ++spt) {
        const int col = spt * 16 + llo;
        const int pnhwc = (img * 1024 + row * 32 + col) * 128 + co0;
        const int idx0  = img * CHW_ + co0 * 1024 + row * 32 + col;
        u16x4 pk;
        #pragma unroll
        for (int reg = 0; reg < 4; ++reg) {
          float kv = a2[q][spt][reg] + bia[reg];
          int id = idx0 + reg * 1024;
          float tv;
          if constexpr (ST == 1)      { float yv = ypre[q][spt][reg]; acc32[id] = yv + dt6 * kv; tv = yv + dth * kv; }
          else if constexpr (ST == 2) { float yv = ypre[q][spt][reg]; acc32[id] = apre[q][spt][reg] + dt3 * kv; tv = yv + dth * kv; }
          else if constexpr (ST == 3) { float yv = ypre[q][spt][reg]; acc32[id] = apre[q][spt][reg] + dt3 * kv; tv = yv + dt * kv; }
          else {
            tv = apre[q][spt][reg] + dt6 * kv;
            y32[id] = tv;
            dout[(img * 25 + step + 1) * CHW_ + co0 * 1024 + row * 32 + col + reg * 1024] = tv;
          }
          pk[reg] = f2bf(tv);
        }
        *(u16x4*)(tmp_bf + pnhwc) = pk;
      }
    }
  }
}

extern "C" void kernel_launch(void* const* d_in, const int* in_sizes, int n_in,
                              void* d_out, int out_size, void* d_ws, size_t ws_size,
                              hipStream_t stream) {
  const float* y0   = (const float*)d_in[0];
  const float* tarr = (const float*)d_in[1];
  const float* W1   = (const float*)d_in[2];
  const float* b1   = (const float*)d_in[3];
  const float* W2   = (const float*)d_in[4];
  const float* b2   = (const float*)d_in[5];
  float* dout = (float*)d_out;

  char* ws = (char*)d_ws;
  float* y32             = (float*)(ws);                          // 8 MB (NCHW)
  float* acc32           = (float*)(ws + (8u << 20));             // 8 MB (NCHW)
  unsigned short* tmp_bf = (unsigned short*)(ws + (16u << 20));   // 4 MB (NHWC)
  unsigned short* w1bf   = (unsigned short*)(ws + (20u << 20));   // 288 KB
  unsigned short* w2bf   = (unsigned short*)(ws + (20u << 20) + 294912);

  prep_weights<<<(2 * 147456 + 255) / 256, 256, 0, stream>>>(W1, W2, w1bf, w2bf);
  init_copy<<<(B_ * CHW_ + 255) / 256, 256, 0, stream>>>(y0, y32, dout);
  init_transpose<<<2048, 256, 0, stream>>>(y0, tmp_bf);

  for (int step = 0; step < 24; ++step) {
    fused_stage<1><<<256, 512, 0, stream>>>(w1bf, w2bf, b1, b2, tmp_bf, y32, acc32, dout, tarr, step);
    fused_stage<2><<<256, 512, 0, stream>>>(w1bf, w2bf, b1, b2, tmp_bf, y32, acc32, dout, tarr, step);
    fused_stage<3><<<256, 512, 0, stream>>>(w1bf, w2bf, b1, b2, tmp_bf, y32, acc32, dout, tarr, step);
    fused_stage<4><<<256, 512, 0, stream>>>(w1bf, w2bf, b1, b2, tmp_bf, y32, acc32, dout, tarr, step);
  }
}